// Round 2
// baseline (1859.966 us; speedup 1.0000x reference)
//
#include <hip/hip_runtime.h>
#include <hip/hip_bf16.h>

using bf16 = __hip_bfloat16;
typedef __attribute__((ext_vector_type(8))) short bf16x8;
typedef __attribute__((ext_vector_type(4))) float f32x4;
typedef const __attribute__((address_space(1))) unsigned int* gp_t;  // global
typedef __attribute__((address_space(3))) unsigned int* sp_t;       // LDS

#define B_   2
#define S_   2048
#define D_   2048
#define H_   16
#define HD_  128
#define F_   8192
#define LC_  512
#define ESTRIDE (6*D_)   // em is (B,6,D); per-b stride

// ---------------- block reduction helpers (256 threads, 4 waves) ------------
__device__ __forceinline__ float bsum4(float v, float* rs) {
  #pragma unroll
  for (int o = 32; o; o >>= 1) v += __shfl_down(v, o, 64);
  int lane = threadIdx.x & 63, w = threadIdx.x >> 6;
  if (!lane) rs[w] = v;
  __syncthreads();
  float r = rs[0] + rs[1] + rs[2] + rs[3];
  __syncthreads();
  return r;
}
__device__ __forceinline__ float bmax4(float v, float* rs) {
  #pragma unroll
  for (int o = 32; o; o >>= 1) v = fmaxf(v, __shfl_down(v, o, 64));
  int lane = threadIdx.x & 63, w = threadIdx.x >> 6;
  if (!lane) rs[w] = v;
  __syncthreads();
  float r = fmaxf(fmaxf(rs[0], rs[1]), fmaxf(rs[2], rs[3]));
  __syncthreads();
  return r;
}

// counted-vmcnt wait as a callable expression (asm is a statement, not expr)
template <int N>
__device__ __forceinline__ void vmwait() {
  asm volatile("s_waitcnt vmcnt(%0)" :: "n"(N) : "memory");
}
__device__ __forceinline__ void vmnone() {}

// ---------------- small elementwise kernels ---------------------------------
__global__ void k_addmod(const float* __restrict__ e, const float* __restrict__ mod,
                         float* __restrict__ em) {
  int i = blockIdx.x * 256 + threadIdx.x;        // B*6*D total
  em[i] = e[i] + mod[i % (6 * D_)];
}

__global__ void k_f2b(const float* __restrict__ in, bf16* __restrict__ out) {
  int i = blockIdx.x * 256 + threadIdx.x;
  out[i] = __float2bfloat16(in[i]);
}

__global__ void k_copy_f32(const float* __restrict__ in, float* __restrict__ out) {
  int i = blockIdx.x * 256 + threadIdx.x;
  out[i] = in[i];
}

// transpose+convert weights: in (K,N) f32 -> out (N,K) bf16
__global__ void k_tr_f2b(const float* __restrict__ in, bf16* __restrict__ out,
                         int K, int N) {
  __shared__ float tile[64][65];
  int kb = blockIdx.y << 6, nb = blockIdx.x << 6;
  int x = threadIdx.x & 63, y = threadIdx.x >> 6;
  #pragma unroll
  for (int r = y; r < 64; r += 4) tile[r][x] = in[(size_t)(kb + r) * N + nb + x];
  __syncthreads();
  #pragma unroll
  for (int r = y; r < 64; r += 4)
    out[(size_t)(nb + r) * K + kb + x] = __float2bfloat16(tile[x][r]);
}

// bf16 transpose, batched over z: in (R,C) -> out (C,R)
__global__ void k_tr_b2b(const bf16* __restrict__ in, bf16* __restrict__ out,
                         int R, int C, long long sIn, long long sOut) {
  in  += (long long)blockIdx.z * sIn;
  out += (long long)blockIdx.z * sOut;
  __shared__ bf16 tile[64][65];
  int rb = blockIdx.y << 6, cb = blockIdx.x << 6;
  int x = threadIdx.x & 63, y = threadIdx.x >> 6;
  #pragma unroll
  for (int r = y; r < 64; r += 4) tile[r][x] = in[(size_t)(rb + r) * C + cb + x];
  __syncthreads();
  #pragma unroll
  for (int r = y; r < 64; r += 4) out[(size_t)(cb + r) * R + rb + x] = tile[x][r];
}

// tx = LN(x) * (1 + e_i1) + e_i0, one block per row of 2048, bf16 out
__global__ void k_ln_mod(const float* __restrict__ x, const float* __restrict__ em,
                         int i0, int i1, bf16* __restrict__ out, int s_per_b) {
  __shared__ float rs[4];
  int row = blockIdx.x, t = threadIdx.x;
  int b = row / s_per_b;
  const float* xr = x + (size_t)row * D_;
  float vals[8], s = 0.f, ss = 0.f;
  #pragma unroll
  for (int j = 0; j < 8; j++) {
    float v = xr[t + j * 256];
    vals[j] = v; s += v; ss += v * v;
  }
  s  = bsum4(s, rs);
  ss = bsum4(ss, rs);
  float mean = s * (1.f / D_);
  float var  = ss * (1.f / D_) - mean * mean;
  float inv  = rsqrtf(var + 1e-6f);
  const float* e0 = em + ((size_t)b * 6 + i0) * D_;
  const float* e1 = em + ((size_t)b * 6 + i1) * D_;
  bf16* orow = out + (size_t)row * D_;
  #pragma unroll
  for (int j = 0; j < 8; j++) {
    int c = t + j * 256;
    orow[c] = __float2bfloat16((vals[j] - mean) * inv * (1.f + e1[c]) + e0[c]);
  }
}

// in-place rmsnorm over 2048 (+optional RoPE per 128-dim head), bf16 buffer
__global__ void k_rms_rope(bf16* __restrict__ buf, const float* __restrict__ w,
                           const float* __restrict__ freqs, int do_rope, int s_per_b) {
  __shared__ float rs[4];
  int row = blockIdx.x, t = threadIdx.x;
  bf16* pr = buf + (size_t)row * D_;
  float4 raw = *(const float4*)(pr + (size_t)t * 8);
  bf16* hb = (bf16*)&raw;
  float v[8], ss = 0.f;
  #pragma unroll
  for (int j = 0; j < 8; j++) { v[j] = __bfloat162float(hb[j]); ss += v[j] * v[j]; }
  ss = bsum4(ss, rs);
  float inv = rsqrtf(ss * (1.f / D_) + 1e-6f);
  int base = t * 8;
  #pragma unroll
  for (int j = 0; j < 8; j++) v[j] = v[j] * inv * w[base + j];
  if (do_rope) {
    int s = row % s_per_b;
    const float* fr = freqs + (size_t)s * (HD_ / 2) + ((base & (HD_ - 1)) >> 1);
    #pragma unroll
    for (int p = 0; p < 4; p++) {
      float ang = fr[p];
      float c = cosf(ang), sn = sinf(ang);
      float xr = v[2 * p], xi = v[2 * p + 1];
      v[2 * p]     = xr * c - xi * sn;
      v[2 * p + 1] = xr * sn + xi * c;
    }
  }
  float4 ow; bf16* ho = (bf16*)&ow;
  #pragma unroll
  for (int j = 0; j < 8; j++) ho[j] = __float2bfloat16(v[j]);
  *(float4*)(pr + (size_t)t * 8) = ow;
}

// in-place row softmax on bf16 scores, row length N = EPT*256
template <int EPT>
__global__ void k_softmax(bf16* __restrict__ buf, int N) {
  __shared__ float rs[4];
  int row = blockIdx.x, t = threadIdx.x;
  bf16* pr = buf + (size_t)row * N;
  float v[EPT], mx = -1e30f;
  #pragma unroll
  for (int j = 0; j < EPT; j++) { v[j] = __bfloat162float(pr[t + j * 256]); mx = fmaxf(mx, v[j]); }
  mx = bmax4(mx, rs);
  float s = 0.f;
  #pragma unroll
  for (int j = 0; j < EPT; j++) { v[j] = __expf(v[j] - mx); s += v[j]; }
  s = bsum4(s, rs);
  float invs = 1.f / s;
  #pragma unroll
  for (int j = 0; j < EPT; j++) pr[t + j * 256] = __float2bfloat16(v[j] * invs);
}

// XCD-stripe swizzle (bijective when nx%8==0)
__device__ __forceinline__ void xcd_swizzle(int& bx, int& by) {
  int nx = gridDim.x, ny = gridDim.y;
  if ((nx & 7) == 0) {
    int flat = by * nx + bx;
    int xcd = flat & 7;
    int idx = flat >> 3;
    int sx = nx >> 3;
    bx = xcd * sx + (idx % sx);
    by = idx / sx;
    (void)ny;
  }
}

// ---------------- legacy 128x128 MFMA GEMM (kept for K=128 QK and M=1024) ---
// C = A(M,K) @ Bt(N,K)^T.  EPI 0: bias->bf16;  EPI 1: *scale->bf16
template <int EPI>
__global__ __launch_bounds__(256) void gemm_bt(
    const bf16* __restrict__ A, int lda, long long sA,
    const bf16* __restrict__ Bt, int ldb, long long sB,
    const float* __restrict__ bias,
    bf16* __restrict__ Cb, int ldc, long long sCb,
    float* __restrict__ Cf, const float* __restrict__ Xin,
    float scale, const float* __restrict__ evec, int s_per_b,
    int K) {
  __shared__ __align__(16) bf16 As[128][32];
  __shared__ __align__(16) bf16 Bs[128][32];
  const int z = blockIdx.z;
  A  += (long long)z * sA;
  Bt += (long long)z * sB;
  int bx = blockIdx.x, by = blockIdx.y;
  xcd_swizzle(bx, by);
  const int m0 = by * 128, n0 = bx * 128;
  const int t = threadIdx.x;
  const int w = t >> 6, lane = t & 63;
  const int wrow = (w >> 1) * 64, wcol = (w & 1) * 64;
  const int quad = lane >> 4, l16 = lane & 15;

  f32x4 zero = {0.f, 0.f, 0.f, 0.f};
  f32x4 acc[4][4];
  #pragma unroll
  for (int i = 0; i < 4; i++)
    #pragma unroll
    for (int j = 0; j < 4; j++) acc[i][j] = zero;

  for (int k0 = 0; k0 < K; k0 += 32) {
    #pragma unroll
    for (int i = 0; i < 2; i++) {
      int c = t + i * 256;
      int r = c >> 2, col = (c & 3) * 8;
      __builtin_amdgcn_global_load_lds(
          (gp_t)(A + (size_t)(m0 + r) * lda + k0 + col),
          (sp_t)(&As[0][0] + (size_t)(w * 64 + i * 256) * 8), 16, 0, 0);
      __builtin_amdgcn_global_load_lds(
          (gp_t)(Bt + (size_t)(n0 + r) * ldb + k0 + col),
          (sp_t)(&Bs[0][0] + (size_t)(w * 64 + i * 256) * 8), 16, 0, 0);
    }
    __syncthreads();
    bf16x8 af[4], bfr[4];
    #pragma unroll
    for (int mi = 0; mi < 4; mi++) af[mi]  = *(const bf16x8*)(&As[wrow + mi * 16 + l16][quad * 8]);
    #pragma unroll
    for (int ni = 0; ni < 4; ni++) bfr[ni] = *(const bf16x8*)(&Bs[wcol + ni * 16 + l16][quad * 8]);
    #pragma unroll
    for (int mi = 0; mi < 4; mi++)
      #pragma unroll
      for (int ni = 0; ni < 4; ni++)
        acc[mi][ni] = __builtin_amdgcn_mfma_f32_16x16x32_bf16(af[mi], bfr[ni], acc[mi][ni], 0, 0, 0);
    __syncthreads();
  }

  #pragma unroll
  for (int mi = 0; mi < 4; mi++) {
    #pragma unroll
    for (int r = 0; r < 4; r++) {
      int gm = m0 + wrow + mi * 16 + quad * 4 + r;
      #pragma unroll
      for (int ni = 0; ni < 4; ni++) {
        int gn = n0 + wcol + ni * 16 + l16;
        float v = acc[mi][ni][r];
        if (EPI == 0) {
          if (bias) v += bias[gn];
          Cb[(long long)z * sCb + (size_t)gm * ldc + gn] = __float2bfloat16(v);
        } else if (EPI == 1) {
          Cb[(long long)z * sCb + (size_t)gm * ldc + gn] = __float2bfloat16(v * scale);
        }
      }
    }
  }
}

// 64x64-tile GEMM (no bias/epilogue) for narrow-N problems (PV: N=128).
__global__ __launch_bounds__(256) void gemm64(
    const bf16* __restrict__ A, int lda, long long sA,
    const bf16* __restrict__ Bt, int ldb, long long sB,
    bf16* __restrict__ Cb, int ldc, long long sCb,
    int K) {
  __shared__ __align__(16) bf16 As[64][32];
  __shared__ __align__(16) bf16 Bs[64][32];
  const int z = blockIdx.z;
  A  += (long long)z * sA;
  Bt += (long long)z * sB;
  const int m0 = blockIdx.y * 64, n0 = blockIdx.x * 64;
  const int t = threadIdx.x;
  const int w = t >> 6, lane = t & 63;
  const int wrow = (w >> 1) * 32, wcol = (w & 1) * 32;
  const int quad = lane >> 4, l16 = lane & 15;

  f32x4 zero = {0.f, 0.f, 0.f, 0.f};
  f32x4 acc[2][2];
  #pragma unroll
  for (int i = 0; i < 2; i++)
    #pragma unroll
    for (int j = 0; j < 2; j++) acc[i][j] = zero;

  for (int k0 = 0; k0 < K; k0 += 32) {
    {
      int r = t >> 2, col = (t & 3) * 8;
      __builtin_amdgcn_global_load_lds(
          (gp_t)(A + (size_t)(m0 + r) * lda + k0 + col),
          (sp_t)(&As[0][0] + (size_t)(w * 64) * 8), 16, 0, 0);
      __builtin_amdgcn_global_load_lds(
          (gp_t)(Bt + (size_t)(n0 + r) * ldb + k0 + col),
          (sp_t)(&Bs[0][0] + (size_t)(w * 64) * 8), 16, 0, 0);
    }
    __syncthreads();
    bf16x8 af[2], bfr[2];
    #pragma unroll
    for (int mi = 0; mi < 2; mi++) af[mi]  = *(const bf16x8*)(&As[wrow + mi * 16 + l16][quad * 8]);
    #pragma unroll
    for (int ni = 0; ni < 2; ni++) bfr[ni] = *(const bf16x8*)(&Bs[wcol + ni * 16 + l16][quad * 8]);
    #pragma unroll
    for (int mi = 0; mi < 2; mi++)
      #pragma unroll
      for (int ni = 0; ni < 2; ni++)
        acc[mi][ni] = __builtin_amdgcn_mfma_f32_16x16x32_bf16(af[mi], bfr[ni], acc[mi][ni], 0, 0, 0);
    __syncthreads();
  }

  #pragma unroll
  for (int mi = 0; mi < 2; mi++) {
    #pragma unroll
    for (int r = 0; r < 4; r++) {
      int gm = m0 + wrow + mi * 16 + quad * 4 + r;
      #pragma unroll
      for (int ni = 0; ni < 2; ni++) {
        int gn = n0 + wcol + ni * 16 + l16;
        Cb[(long long)z * sCb + (size_t)gm * ldc + gn] = __float2bfloat16(acc[mi][ni][r]);
      }
    }
  }
}

// =================== 8-phase 256-row pipelined GEMM (T1+T2+T3+T4+T5) ========
// BM=256 fixed, BK=64, 512 threads (8 waves).  BN in {256,128}.
// LDS swizzle: byte ^= (row&7)<<4, applied as inverse-swizzled global source
// (global_load_lds writes linearly) + swizzled ds_read (rule #21).
// Stage one half-tile per load call: half = 128 A-rows (2x8KB) or BN/2 B-rows.
__device__ __forceinline__ void stage_half2(const bf16* P, int ld, int grow0,
                                            int k0, bf16* ldshalf, int w, int lane) {
  #pragma unroll
  for (int j = 0; j < 2; j++) {
    int offw = j * 8192 + w * 1024;        // wave-uniform LDS byte offset
    int off  = offw + lane * 16;           // this lane's linear byte slot
    int r = off >> 7;                      // row within half (128B rows)
    int chunk = ((off >> 4) & 7) ^ (r & 7);// inverse-swizzled source chunk
    __builtin_amdgcn_global_load_lds(
        (gp_t)(P + (size_t)(grow0 + r) * ld + k0 + chunk * 8),
        (sp_t)((char*)ldshalf + offw), 16, 0, 0);
  }
}
__device__ __forceinline__ void stage_half1(const bf16* P, int ld, int grow0,
                                            int k0, bf16* ldshalf, int w, int lane) {
  int offw = w * 1024;
  int off  = offw + lane * 16;
  int r = off >> 7;
  int chunk = ((off >> 4) & 7) ^ (r & 7);
  __builtin_amdgcn_global_load_lds(
      (gp_t)(P + (size_t)(grow0 + r) * ld + k0 + chunk * 8),
      (sp_t)((char*)ldshalf + offw), 16, 0, 0);
}

// one phase: quadrant (AH,BH) of the current tile + one half-tile prefetch.
// reads happen before stage-issue; sched_barrier(0) at phase top pins motion.
#define PHASE(AH, BH, CURB, STAGE_STMT, VM_STMT) do {                          \
    __builtin_amdgcn_sched_barrier(0);                                         \
    bf16x8 af[FI][2], bv[2][2];                                                \
    const char* aB = (const char*)&As[(CURB)][0][0];                           \
    const char* bB = (const char*)&Bs[(CURB)][0][0];                           \
    _Pragma("unroll")                                                          \
    for (int fi = 0; fi < FI; fi++) {                                          \
      int ar = wm * RH + (AH) * 128 + fi * 16 + l16;                           \
      _Pragma("unroll")                                                        \
      for (int ks = 0; ks < 2; ks++)                                           \
        af[fi][ks] = *(const bf16x8*)(aB + ar * 128 +                          \
                                      ((64 * ks + 16 * quad) ^ swz));          \
    }                                                                          \
    _Pragma("unroll")                                                          \
    for (int fj = 0; fj < 2; fj++) {                                           \
      int br = wn * 32 + (BH) * CHALF + fj * 16 + l16;                         \
      _Pragma("unroll")                                                        \
      for (int ks = 0; ks < 2; ks++)                                           \
        bv[fj][ks] = *(const bf16x8*)(bB + br * 128 +                          \
                                      ((64 * ks + 16 * quad) ^ swz));          \
    }                                                                          \
    STAGE_STMT;                                                                \
    VM_STMT;                                                                   \
    __builtin_amdgcn_s_barrier();                                              \
    __builtin_amdgcn_s_setprio(1);                                             \
    _Pragma("unroll")                                                          \
    for (int fi = 0; fi < FI; fi++)                                            \
      _Pragma("unroll")                                                        \
      for (int fj = 0; fj < 2; fj++)                                           \
        _Pragma("unroll")                                                      \
        for (int ks = 0; ks < 2; ks++)                                         \
          acc[(AH)][(BH)][fi][fj] = __builtin_amdgcn_mfma_f32_16x16x32_bf16(   \
              af[fi][ks], bv[fj][ks], acc[(AH)][(BH)][fi][fj], 0, 0, 0);       \
    __builtin_amdgcn_s_setprio(0);                                             \
    __builtin_amdgcn_s_barrier();                                              \
  } while (0)

// EPI 0: bias->bf16 | EPI 2: f32 residual (+optional evec, optional bf16 mirror)
// EPI 3: gelu(bias+acc)->bf16
template <int EPI, int BN, int WM, int WN>
__global__ __launch_bounds__(512, 2) void gemm256(
    const bf16* __restrict__ A, int lda, long long sA,
    const bf16* __restrict__ Bt, int ldb, long long sB,
    const float* __restrict__ bias,
    bf16* __restrict__ Cb, int ldc, long long sCb,
    float* __restrict__ Cf, const float* __restrict__ Xin,
    float scale, const float* __restrict__ evec, int s_per_b, int K) {
  constexpr int RH = 256 / (WM * 2);       // rows per wave per A-half
  constexpr int FI = RH / 16;              // A-fragments per quadrant
  constexpr int CHALF = BN / 2;            // rows per B-half
  constexpr int LB = (BN == 256) ? 2 : 1;  // load-instrs per B-half
  constexpr int PRO_V = 2 + LB;            // leave t1's {Ah0,Bh1} in flight
  constexpr int P2_V = (BN == 256) ? 8 : 6;// derived counted waits (see notes)
  constexpr int P4_V = (BN == 256) ? 6 : 5;

  __shared__ __align__(16) bf16 As[2][256][64];
  __shared__ __align__(16) bf16 Bs[2][BN][64];

  const int z = blockIdx.z;
  A  += (long long)z * sA;
  Bt += (long long)z * sB;
  int bx = blockIdx.x, by = blockIdx.y;
  xcd_swizzle(bx, by);
  const int m0 = by * 256, n0 = bx * BN;
  const int t = threadIdx.x;
  const int w = t >> 6, lane = t & 63;
  const int wm = w / WN, wn = w % WN;
  const int quad = lane >> 4, l16 = lane & 15;
  const int swz = (l16 & 7) << 4;

  f32x4 zero = {0.f, 0.f, 0.f, 0.f};
  f32x4 acc[2][2][FI][2];
  #pragma unroll
  for (int a = 0; a < 2; a++)
    #pragma unroll
    for (int b = 0; b < 2; b++)
      #pragma unroll
      for (int i = 0; i < FI; i++)
        #pragma unroll
        for (int j = 0; j < 2; j++) acc[a][b][i][j] = zero;

  const int NT = K >> 6;   // K-tiles of 64; callers guarantee NT >= 2

  // prologue: tile0 fully {Ah0,Bh0,Bh1,Ah1}; tile1 partially {Ah0,Bh1}
  stage_half2(A, lda, m0,        0, &As[0][0][0],     w, lane);
  if (LB == 2) stage_half2(Bt, ldb, n0,        0, &Bs[0][0][0],     w, lane);
  else         stage_half1(Bt, ldb, n0,        0, &Bs[0][0][0],     w, lane);
  if (LB == 2) stage_half2(Bt, ldb, n0 + CHALF, 0, &Bs[0][CHALF][0], w, lane);
  else         stage_half1(Bt, ldb, n0 + CHALF, 0, &Bs[0][CHALF][0], w, lane);
  stage_half2(A, lda, m0 + 128,  0, &As[0][128][0],   w, lane);
  stage_half2(A, lda, m0,       64, &As[1][0][0],     w, lane);
  if (LB == 2) stage_half2(Bt, ldb, n0 + CHALF, 64, &Bs[1][CHALF][0], w, lane);
  else         stage_half1(Bt, ldb, n0 + CHALF, 64, &Bs[1][CHALF][0], w, lane);
  vmwait<PRO_V>();
  __builtin_amdgcn_s_barrier();

  for (int tt = 0; tt < NT; tt++) {
    const int cur = tt & 1, nxt = cur ^ 1;
    const int w1 = (tt + 1 < NT) ? tt + 1 : 0;          // wrapped (dead) tail
    const int w2 = (tt + 2 < NT) ? tt + 2 : tt + 2 - NT;
    // p1: Q(A0,B0); stage (t+1).Bh0 -> nxt (Bh0 of cur read only p1,p4: nxt buf ok)
    PHASE(0, 0, cur,
          (LB == 2 ? stage_half2(Bt, ldb, n0, w1 * 64, &Bs[nxt][0][0], w, lane)
                   : stage_half1(Bt, ldb, n0, w1 * 64, &Bs[nxt][0][0], w, lane)),
          vmnone());
    // p2: Q(A0,B1); stage (t+1).Ah1 -> nxt; counted wait: (t,Ah1) landed
    PHASE(0, 1, cur,
          (stage_half2(A, lda, m0 + 128, w1 * 64, &As[nxt][128][0], w, lane)),
          vmwait<P2_V>());
    // p3: Q(A1,B1); stage (t+2).Ah0 -> cur (Ah0 reads were p1,p2: safe)
    PHASE(1, 1, cur,
          (stage_half2(A, lda, m0, w2 * 64, &As[cur][0][0], w, lane)),
          vmnone());
    // p4: Q(A1,B0); stage (t+2).Bh1 -> cur (Bh1 reads were p2,p3: safe);
    //     counted wait: (t+1).{Ah0,Bh0} landed, 3 half-tiles stay in flight
    PHASE(1, 0, cur,
          (LB == 2 ? stage_half2(Bt, ldb, n0 + CHALF, w2 * 64, &Bs[cur][CHALF][0], w, lane)
                   : stage_half1(Bt, ldb, n0 + CHALF, w2 * 64, &Bs[cur][CHALF][0], w, lane)),
          vmwait<P4_V>());
  }
  // drain LDS-DMA before epilogue / endpgm
  asm volatile("s_waitcnt vmcnt(0)" ::: "memory");

  #pragma unroll
  for (int ah = 0; ah < 2; ah++)
    #pragma unroll
    for (int fi = 0; fi < FI; fi++)
      #pragma unroll
      for (int r = 0; r < 4; r++) {
        int gm = m0 + wm * RH + ah * 128 + fi * 16 + quad * 4 + r;
        #pragma unroll
        for (int bh = 0; bh < 2; bh++)
          #pragma unroll
          for (int fj = 0; fj < 2; fj++) {
            int gn = n0 + wn * 32 + bh * CHALF + fj * 16 + l16;
            float v = acc[ah][bh][fi][fj][r];
            if (EPI == 0) {
              if (bias) v += bias[gn];
              Cb[(long long)z * sCb + (size_t)gm * ldc + gn] = __float2bfloat16(v);
            } else if (EPI == 3) {
              v += bias[gn];
              float u = 1.5957691216057308f * (v + 0.044715f * v * v * v);
              float g = v / (1.f + __expf(-u));   // == 0.5v(1+tanh(u/2)) form
              Cb[(long long)z * sCb + (size_t)gm * ldc + gn] = __float2bfloat16(g);
            } else {  // EPI 2: residual
              v += bias[gn];
              if (evec) v *= evec[(size_t)(gm / s_per_b) * ESTRIDE + gn];
              float o = Xin[(size_t)gm * ldc + gn] + v;
              Cf[(size_t)gm * ldc + gn] = o;
              if (Cb) Cb[(size_t)gm * ldc + gn] = __float2bfloat16(o);
            }
          }
      }
  (void)scale;
}

// ---------------- host orchestration ----------------------------------------
extern "C" void kernel_launch(void* const* d_in, const int* in_sizes, int n_in,
                              void* d_out, int out_size, void* d_ws, size_t ws_size,
                              hipStream_t stream) {
  const float* x     = (const float*)d_in[0];
  const float* e     = (const float*)d_in[1];
  const float* ctx   = (const float*)d_in[2];
  const float* freqs = (const float*)d_in[3];
  const float* modu  = (const float*)d_in[4];
  const float* sq_w = (const float*)d_in[5];  const float* sq_b = (const float*)d_in[6];
  const float* sk_w = (const float*)d_in[7];  const float* sk_b = (const float*)d_in[8];
  const float* sv_w = (const float*)d_in[9];  const float* sv_b = (const float*)d_in[10];
  const float* so_w = (const float*)d_in[11]; const float* so_b = (const float*)d_in[12];
  const float* cq_w = (const float*)d_in[13]; const float* cq_b = (const float*)d_in[14];
  const float* ck_w = (const float*)d_in[15]; const float* ck_b = (const float*)d_in[16];
  const float* cv_w = (const float*)d_in[17]; const float* cv_b = (const float*)d_in[18];
  const float* co_w = (const float*)d_in[19]; const float* co_b = (const float*)d_in[20];
  const float* f1_w = (const float*)d_in[21]; const float* f1_b = (const float*)d_in[22];
  const float* f2_w = (const float*)d_in[23]; const float* f2_b = (const float*)d_in[24];
  const float* snq  = (const float*)d_in[25]; const float* snk  = (const float*)d_in[26];
  const float* cnq  = (const float*)d_in[27]; const float* cnk  = (const float*)d_in[28];
  float* out = (float*)d_out;     // doubles as the f32 residual accumulator

  const size_t MD = (size_t)B_ * S_ * D_;   // 8.39M elems

  char* W = (char*)d_ws;
  size_t off = 0;
  auto alloc = [&](size_t bytes) -> char* {
    char* p = W + off; off += (bytes + 255) & ~(size_t)255; return p;
  };
  float* em  = (float*)alloc((size_t)B_ * 6 * D_ * 4);
  bf16* wT   = (bf16*)alloc((size_t)F_ * D_ * 2);   // transposed weights (f1-sized)
  bf16* vb   = (bf16*)alloc(MD * 2);
  bf16* tx   = (bf16*)alloc(MD * 2);
  bf16* qb   = (bf16*)alloc(MD * 2);
  bf16* kb   = (bf16*)alloc(MD * 2);
  bf16* vt   = (bf16*)alloc(MD * 2);
  bf16* attnout = (bf16*)alloc(MD * 2);
  bf16* ctxb = (bf16*)alloc((size_t)B_ * LC_ * D_ * 2);
  bf16* kc   = (bf16*)alloc((size_t)B_ * LC_ * D_ * 2);
  bf16* vc   = (bf16*)alloc((size_t)B_ * LC_ * D_ * 2);
  bf16* vtc  = (bf16*)alloc((size_t)B_ * LC_ * D_ * 2);
  bf16* scores8 = wT;   // 8-head self-attn scores: spans wT|vb|tx (all dead then)
  bf16* scoresC = wT;   // cross-attn scores
  bf16* mid = qb;       // FFN mid: spans qb|kb|vt|attnout
  if (off > ws_size) {
    k_copy_f32<<<(int)(MD / 256), 256, 0, stream>>>(x, out);
    return;
  }

  const float qk_scale = 0.08838834764831845f;  // 1/sqrt(128)

  // ---- prep ----
  k_addmod<<<(B_ * 6 * D_) / 256, 256, 0, stream>>>(e, modu, em);
  k_f2b<<<(B_ * LC_ * D_) / 256, 256, 0, stream>>>(ctx, ctxb);

  // ---- self-attention branch ----
  k_ln_mod<<<B_ * S_, 256, 0, stream>>>(x, em, 0, 1, tx, S_);
  k_tr_f2b<<<dim3(D_ / 64, D_ / 64), 256, 0, stream>>>(sq_w, wT, D_, D_);
  gemm256<0, 128, 4, 2><<<dim3(16, 16, 1), 512, 0, stream>>>(tx, D_, 0, wT, D_, 0, sq_b,
      qb, D_, 0, nullptr, nullptr, 1.f, nullptr, S_, D_);
  k_tr_f2b<<<dim3(D_ / 64, D_ / 64), 256, 0, stream>>>(sk_w, wT, D_, D_);
  gemm256<0, 128, 4, 2><<<dim3(16, 16, 1), 512, 0, stream>>>(tx, D_, 0, wT, D_, 0, sk_b,
      kb, D_, 0, nullptr, nullptr, 1.f, nullptr, S_, D_);
  k_tr_f2b<<<dim3(D_ / 64, D_ / 64), 256, 0, stream>>>(sv_w, wT, D_, D_);
  gemm256<0, 128, 4, 2><<<dim3(16, 16, 1), 512, 0, stream>>>(tx, D_, 0, wT, D_, 0, sv_b,
      vb, D_, 0, nullptr, nullptr, 1.f, nullptr, S_, D_);
  k_rms_rope<<<B_ * S_, 256, 0, stream>>>(qb, snq, freqs, 1, S_);
  k_rms_rope<<<B_ * S_, 256, 0, stream>>>(kb, snk, freqs, 1, S_);
  k_tr_b2b<<<dim3(D_ / 64, S_ / 64, B_), 256, 0, stream>>>(vb, vt, S_, D_,
      (long long)S_ * D_, (long long)D_ * S_);
  // from here wT, vb, tx are dead -> scores8 overlay is live

  for (int b = 0; b < B_; b++) {
    for (int hc = 0; hc < 2; hc++) {  // 8 heads per chunk
      const int h0 = hc * 8;
      const bf16* Aq = qb + (size_t)b * S_ * D_ + h0 * HD_;
      const bf16* Bk = kb + (size_t)b * S_ * D_ + h0 * HD_;
      gemm_bt<1><<<dim3(16, 16, 8), 256, 0, stream>>>(Aq, D_, HD_, Bk, D_, HD_, nullptr,
          scores8, S_, (long long)S_ * S_, nullptr, nullptr, qk_scale, nullptr, S_, HD_);
      k_softmax<8><<<8 * S_, 256, 0, stream>>>(scores8, S_);
      const bf16* Bv = vt + ((size_t)b * D_ + h0 * HD_) * S_;
      gemm64<<<dim3(2, 32, 8), 256, 0, stream>>>(scores8, S_, (long long)S_ * S_,
          Bv, S_, (long long)HD_ * S_,
          attnout + (size_t)b * S_ * D_ + h0 * HD_, D_, HD_, S_);
    }
  }
  // out = x + (attn @ so_w + so_b) * e2 ; also write tx = bf16(out)
  k_tr_f2b<<<dim3(D_ / 64, D_ / 64), 256, 0, stream>>>(so_w, wT, D_, D_);
  gemm256<2, 128, 4, 2><<<dim3(16, 16, 1), 512, 0, stream>>>(attnout, D_, 0, wT, D_, 0, so_b,
      tx, D_, 0, out, x, 1.f, em + 2 * D_, S_, D_);

  // ---- cross-attention branch ----
  k_tr_f2b<<<dim3(D_ / 64, D_ / 64), 256, 0, stream>>>(cq_w, wT, D_, D_);
  gemm256<0, 128, 4, 2><<<dim3(16, 16, 1), 512, 0, stream>>>(tx, D_, 0, wT, D_, 0, cq_b,
      qb, D_, 0, nullptr, nullptr, 1.f, nullptr, S_, D_);
  k_rms_rope<<<B_ * S_, 256, 0, stream>>>(qb, cnq, nullptr, 0, S_);
  k_tr_f2b<<<dim3(D_ / 64, D_ / 64), 256, 0, stream>>>(ck_w, wT, D_, D_);
  gemm_bt<0><<<dim3(16, 8, 1), 256, 0, stream>>>(ctxb, D_, 0, wT, D_, 0, ck_b,
      kc, D_, 0, nullptr, nullptr, 1.f, nullptr, S_, D_);
  k_rms_rope<<<B_ * LC_, 256, 0, stream>>>(kc, cnk, nullptr, 0, S_);
  k_tr_f2b<<<dim3(D_ / 64, D_ / 64), 256, 0, stream>>>(cv_w, wT, D_, D_);
  gemm_bt<0><<<dim3(16, 8, 1), 256, 0, stream>>>(ctxb, D_, 0, wT, D_, 0, cv_b,
      vc, D_, 0, nullptr, nullptr, 1.f, nullptr, S_, D_);
  k_tr_b2b<<<dim3(D_ / 64, LC_ / 64, B_), 256, 0, stream>>>(vc, vtc, LC_, D_,
      (long long)LC_ * D_, (long long)D_ * LC_);

  for (int b = 0; b < B_; b++) {  // all 16 heads at once (16*S*LC*2 = 33.5 MB)
    gemm_bt<1><<<dim3(4, 16, 16), 256, 0, stream>>>(qb + (size_t)b * S_ * D_, D_, HD_,
        kc + (size_t)b * LC_ * D_, D_, HD_, nullptr,
        scoresC, LC_, (long long)S_ * LC_, nullptr, nullptr, qk_scale, nullptr, S_, HD_);
    k_softmax<2><<<16 * S_, 256, 0, stream>>>(scoresC, LC_);
    gemm64<<<dim3(2, 32, 16), 256, 0, stream>>>(scoresC, LC_, (long long)S_ * LC_,
        vtc + (size_t)b * D_ * LC_, LC_, (long long)HD_ * LC_,
        attnout + (size_t)b * S_ * D_, D_, HD_, LC_);
  }
  // out = out + attn @ co_w + co_b
  k_tr_f2b<<<dim3(D_ / 64, D_ / 64), 256, 0, stream>>>(co_w, wT, D_, D_);
  gemm256<2, 128, 4, 2><<<dim3(16, 16, 1), 512, 0, stream>>>(attnout, D_, 0, wT, D_, 0, co_b,
      nullptr, D_, 0, out, out, 1.f, nullptr, S_, D_);

  // ---- FFN ----
  k_ln_mod<<<B_ * S_, 256, 0, stream>>>(out, em, 3, 4, tx, S_);
  k_tr_f2b<<<dim3(F_ / 64, D_ / 64), 256, 0, stream>>>(f1_w, wT, D_, F_);
  gemm256<3, 256, 2, 4><<<dim3(32, 16, 1), 512, 0, stream>>>(tx, D_, 0, wT, D_, 0, f1_b,
      mid, F_, 0, nullptr, nullptr, 1.f, nullptr, S_, D_);
  k_tr_f2b<<<dim3(D_ / 64, F_ / 64), 256, 0, stream>>>(f2_w, wT, F_, D_);
  gemm256<2, 128, 4, 2><<<dim3(16, 16, 1), 512, 0, stream>>>(mid, F_, 0, wT, F_, 0, f2_b,
      nullptr, D_, 0, out, out, 1.f, em + 5 * D_, S_, F_);
}